// Round 11
// baseline (82.002 us; speedup 1.0000x reference)
//
#include <hip/hip_runtime.h>
#include <hip/hip_bf16.h>

typedef __bf16 bf16x8 __attribute__((ext_vector_type(8)));
typedef float  f32x4  __attribute__((ext_vector_type(4)));

#define MFMA(a, b, c) __builtin_amdgcn_mfma_f32_16x16x32_bf16((a), (b), (c), 0, 0, 0)

// R11 = R4 (verified best, 73.4us x2 runs) + coalesced output staging.
// R4 unchanged: n-split, 3 barriers, weight-side hi/lo split, axh reuse,
// no-max-sub softmax. NEW: softmax writes alpha/fused to a 2.3KB LDS staging
// buffer instead of scattered global stores (alpha was 32B granules at 128B
// stride ~50% write eff; fused was 1 dword per 16 lanes). At the next loop-top
// (after barrier 1, which already orders stage-writes(t) vs these reads) all
// 256 threads flush tile t-1 PERFECTLY COALESCED: alpha = 1 float2/thread =
// 2KB contiguous, fused = 64 contiguous dwords. Epilogue flushes the last
// tile after one post-loop barrier. ~23MB of excess HBM write traffic and the
// divergent stores in the softmax loop removed; compute path byte-identical.

__device__ __forceinline__ int swz(int row, int byteInRow) {
    return row * 256 + (byteInRow ^ ((row & 7) << 4));
}

__global__ __launch_bounds__(256, 3) void edge_moe_kernel(
    const float* __restrict__ x,  const float* __restrict__ w1,
    const float* __restrict__ b1, const float* __restrict__ w2,
    const float* __restrict__ b2, const float* __restrict__ wp,
    float* __restrict__ outFused, float* __restrict__ outAlpha, int E)
{
    __shared__ __align__(16) char lds[35072];
    char* XH = lds;                // 16KB
    char* HF = lds + 16384;        // 16KB
    char* OA = lds + 32768;        // [64][8] f32 alpha staging, 2048B
    char* OF = lds + 34816;        // [64] f32 fused staging, 256B

    const int tid  = threadIdx.x;
    const int lane = tid & 63;
    const int wid  = tid >> 6;   // wave id 0..3 = H-col tile owner (n-split)
    const int lc   = lane & 15;
    const int lg   = lane >> 4;

    // ---- Weight B-fragments, split hi/lo on the WEIGHT side ----
    // B-frag (16x16x32): lane holds B[k = kk*32 + lg*8 + j][n], j=0..7.
    bf16x8 w1h[4], w1l[4];       // n = wid*16+lc (this wave's n-tile)
#pragma unroll
    for (int kk = 0; kk < 4; ++kk) {
        bf16x8 h, l;
#pragma unroll
        for (int j = 0; j < 8; ++j) {
            int kidx = kk * 32 + lg * 8 + j;
            float v = w1[kidx * 64 + wid * 16 + lc];
            __bf16 hb = (__bf16)v;
            h[j] = hb; l[j] = (__bf16)(v - (float)hb);
        }
        w1h[kk] = h; w1l[kk] = l;
    }
    bf16x8 w2h[2], w2l[2];       // n = lc (<8), padded 0
#pragma unroll
    for (int kk = 0; kk < 2; ++kk) {
        bf16x8 h, l;
#pragma unroll
        for (int j = 0; j < 8; ++j) {
            int kidx = kk * 32 + lg * 8 + j;
            float v = (lc < 8) ? w2[kidx * 8 + lc] : 0.0f;
            __bf16 hb = (__bf16)v;
            h[j] = hb; l[j] = (__bf16)(v - (float)hb);
        }
        w2h[kk] = h; w2l[kk] = l;
    }
    bf16x8 wph[4], wpl[4];       // n = lc (<8), padded 0
#pragma unroll
    for (int kk = 0; kk < 4; ++kk) {
        bf16x8 h, l;
#pragma unroll
        for (int j = 0; j < 8; ++j) {
            int kidx = kk * 32 + lg * 8 + j;
            float v = (lc < 8) ? wp[kidx * 8 + lc] : 0.0f;
            __bf16 hb = (__bf16)v;
            h[j] = hb; l[j] = (__bf16)(v - (float)hb);
        }
        wph[kk] = h; wpl[kk] = l;
    }
    const float b1v = b1[wid * 16 + lc];          // col fixed per wave (n-split)
    const float b2v = (lc < 8) ? b2[lc] : 0.0f;

    const int ntiles = (E + 63) >> 6;
    const int r0 = tid >> 4;          // 0..15 (x-load row)
    const int c8 = tid & 15;          // 8-float column chunk
    const int arow = wid * 16 + lc;   // this wave's phase-F A-frag row

    long long peb = -1;   // previous tile's edge base (staged outputs pending)

    for (int tile = blockIdx.x; tile < ntiles; tile += gridDim.x) {
        const long long eb = (long long)tile * 64;

        // ---- Load x tile [64][128] f32, coalesced ----
        float4 vr[4][2];
#pragma unroll
        for (int it = 0; it < 4; ++it) {
            long long e = eb + r0 + it * 16;
            if (e > (long long)E - 1) e = E - 1;
            const float4* p = (const float4*)(x + (size_t)e * 128 + c8 * 8);
            vr[it][0] = p[0];
            vr[it][1] = p[1];
        }
        __syncthreads();   // barrier 1: XH/HF(t-1) readers AND OA/OF(t-1) writers done

        // ---- Flush staged outputs of tile t-1, perfectly coalesced ----
        if (peb >= 0) {
            long long edge = peb + (tid >> 2);               // 4 threads per edge
            if (edge < E) {
                float2 v = *(const float2*)(OA + tid * 8);   // flat [tid*2, tid*2+1]
                *(float2*)(outAlpha + edge * 8 + (tid & 3) * 2) = v;
            }
            if (tid < 64) {
                long long edge2 = peb + tid;
                if (edge2 < E) outFused[edge2] = *(const float*)(OF + tid * 4);
            }
        }

        // ---- A: convert to bf16 (hi only), write LDS (swizzled) ----
#pragma unroll
        for (int it = 0; it < 4; ++it) {
            int row = r0 + it * 16;
            bf16x8 h;
            const float* f = (const float*)&vr[it][0];
#pragma unroll
            for (int j = 0; j < 8; ++j) h[j] = (__bf16)f[j];
            *(bf16x8*)(XH + swz(row, c8 * 16)) = h;
        }
        __syncthreads();   // barrier 2: x(t) ready; OA/OF(t-1) reads done

        // ---- D: H = relu(x@w1+b1) for n-tile wid, all 4 m-tiles ----
        // Peel mtt=0 (mt = wid) and stash its A-frags for phase F's x@wp.
        bf16x8 axh[4];
        f32x4 acc[4] = {{0.f,0.f,0.f,0.f},{0.f,0.f,0.f,0.f},{0.f,0.f,0.f,0.f},{0.f,0.f,0.f,0.f}};
#pragma unroll
        for (int kk = 0; kk < 4; ++kk) {
            axh[kk] = *(const bf16x8*)(XH + swz(arow, kk * 64 + lg * 16));
            acc[0] = MFMA(axh[kk], w1h[kk], acc[0]);
            acc[0] = MFMA(axh[kk], w1l[kk], acc[0]);
        }
#pragma unroll
        for (int mtt = 1; mtt < 4; ++mtt) {
            const int mt = (wid + mtt) & 3;
            const int row = mt * 16 + lc;
#pragma unroll
            for (int kk = 0; kk < 4; ++kk) {
                bf16x8 ah = *(const bf16x8*)(XH + swz(row, kk * 64 + lg * 16));
                acc[mtt] = MFMA(ah, w1h[kk], acc[mtt]);
                acc[mtt] = MFMA(ah, w1l[kk], acc[mtt]);
            }
        }
        // bias + relu -> HF f32 (C-layout: row = mt*16+lg*4+r, col = wid*16+lc)
#pragma unroll
        for (int mtt = 0; mtt < 4; ++mtt) {
            const int mt = (wid + mtt) & 3;
#pragma unroll
            for (int r = 0; r < 4; ++r) {
                float hv = fmaxf(acc[mtt][r] + b1v, 0.f);
                *(float*)(HF + swz(mt * 16 + lg * 4 + r, (wid * 16 + lc) * 4)) = hv;
            }
        }
        __syncthreads();   // barrier 3: H ready (cross-wave)

        // ---- F: logits = H@w2 + b2 (H->bf16 once, w2 split); scores from axh ----
        f32x4 lac = {0.f, 0.f, 0.f, 0.f};
        f32x4 sac = {0.f, 0.f, 0.f, 0.f};
#pragma unroll
        for (int kk = 0; kk < 2; ++kk) {
            int base = kk * 128 + lg * 32;     // f32 bytes: k = kk*32 + lg*8
            f32x4 h0 = *(const f32x4*)(HF + swz(arow, base));
            f32x4 h1 = *(const f32x4*)(HF + swz(arow, base + 16));
            bf16x8 hh;
#pragma unroll
            for (int j = 0; j < 4; ++j) {
                hh[j]     = (__bf16)h0[j];
                hh[j + 4] = (__bf16)h1[j];
            }
            lac = MFMA(hh, w2h[kk], lac);
            lac = MFMA(hh, w2l[kk], lac);
        }
#pragma unroll
        for (int kk = 0; kk < 4; ++kk) {
            sac = MFMA(axh[kk], wph[kk], sac);
            sac = MFMA(axh[kk], wpl[kk], sac);
        }

        // ---- Softmax over 8 cols (lanes lc<8; no max-sub) -> LDS staging ----
#pragma unroll
        for (int r = 0; r < 4; ++r) {
            float lv = lac[r] + b2v;           // TEMPERATURE = 1.0
            float p = __expf(lv);
            float s  = p;
            float fs = p * sac[r];
            s  += __shfl_xor(s, 1);  fs += __shfl_xor(fs, 1);
            s  += __shfl_xor(s, 2);  fs += __shfl_xor(fs, 2);
            s  += __shfl_xor(s, 4);  fs += __shfl_xor(fs, 4);
            float inv = 1.0f / s;
            float alpha = p * inv;
            float fv = fs * inv;
            int el = wid * 16 + lg * 4 + r;    // edge_local 0..63
            if (lc < 8) *(float*)(OA + (el * 8 + lc) * 4) = alpha;
            if (lc == 0) *(float*)(OF + el * 4) = fv;
        }
        peb = eb;
        // loop-top barrier 1 orders these staging writes vs next flush reads
    }

    // ---- Epilogue: flush the final staged tile ----
    __syncthreads();
    if (peb >= 0) {
        long long edge = peb + (tid >> 2);
        if (edge < E) {
            float2 v = *(const float2*)(OA + tid * 8);
            *(float2*)(outAlpha + edge * 8 + (tid & 3) * 2) = v;
        }
        if (tid < 64) {
            long long edge2 = peb + tid;
            if (edge2 < E) outFused[edge2] = *(const float*)(OF + tid * 4);
        }
    }
}

extern "C" void kernel_launch(void* const* d_in, const int* in_sizes, int n_in,
                              void* d_out, int out_size, void* d_ws, size_t ws_size,
                              hipStream_t stream) {
    const float* x  = (const float*)d_in[0];
    const float* w1 = (const float*)d_in[1];
    const float* b1 = (const float*)d_in[2];
    const float* w2 = (const float*)d_in[3];
    const float* b2 = (const float*)d_in[4];
    const float* wp = (const float*)d_in[5];

    const int E = in_sizes[0] / 128;
    float* outF = (float*)d_out;
    float* outA = outF + E;

    const int ntiles = (E + 63) >> 6;
    const int blocks = ntiles < 768 ? ntiles : 768;
    edge_moe_kernel<<<blocks, 256, 0, stream>>>(x, w1, b1, w2, b2, wp, outF, outA, E);
}

// Round 12
// 73.348 us; speedup vs baseline: 1.1180x; 1.1180x over previous
//
#include <hip/hip_runtime.h>
#include <hip/hip_bf16.h>

typedef __bf16 bf16x8 __attribute__((ext_vector_type(8)));
typedef float  f32x4  __attribute__((ext_vector_type(4)));

#define MFMA(a, b, c) __builtin_amdgcn_mfma_f32_16x16x32_bf16((a), (b), (c), 0, 0, 0)

// FINAL = R4 verbatim (measured best; reproduced twice: 73.47 / 73.35 us,
// absmax 0.00390625, ~4.77 TB/s effective HBM = 76% of the 6.3 TB/s copy
// ceiling on a 94% read / 6% write mix with interleaved MFMA+LDS+exp).
//
// Structure: 64-edge tile per block-iteration, n-split across 4 waves.
//  - x stored bf16-only in LDS (16KB, XOR-swizzled); hi/lo precision split
//    carried on the WEIGHT side (w1h+w1l, w2h+w2l, wph+wpl in registers).
//  - phase D peels mt==wid and stashes axh[kk] -> phase F's x@wp reuses them.
//  - H via LDS f32 (cross-wave), converted once to bf16, 2 MFMAs vs w2h/w2l.
//  - softmax: no max-subtract (logits bounded), fused sum+dot reduce.
// LDS 32KB -> 3 blocks/CU at __launch_bounds__(256,3).
//
// Optimization ledger (all vs this kernel's 73.4us):
//   R2 whole-round reg prefetch   94.4  (VGPR pressure + barrier vmcnt drain)
//   R3 m-split reg weights       147.5  (spill)
//   R5 global_load_lds direct     FAIL  (swizzle/write-pattern model wrong)
//   R6 occupancy 4 blocks/CU      77.7  (128-VGPR cap spill)
//   R7 late prefetch + 2 barrier  76.8  (prefetch drained at barrier A)
//   R8 barrier-free m-split       77.7  (no change -> not barrier-bound)
//   R9 R8 + early prefetch        88.4  (sched_barrier(0) defeats scheduler)
//   R11 coalesced output staging  82.0  (writes were already merged in L2)
// Conclusion: steady-state practical roofline for this access mix.

__device__ __forceinline__ int swz(int row, int byteInRow) {
    return row * 256 + (byteInRow ^ ((row & 7) << 4));
}

__global__ __launch_bounds__(256, 3) void edge_moe_kernel(
    const float* __restrict__ x,  const float* __restrict__ w1,
    const float* __restrict__ b1, const float* __restrict__ w2,
    const float* __restrict__ b2, const float* __restrict__ wp,
    float* __restrict__ outFused, float* __restrict__ outAlpha, int E)
{
    __shared__ __align__(16) char lds[32768];
    char* XH = lds;
    char* HF = lds + 16384;

    const int tid  = threadIdx.x;
    const int lane = tid & 63;
    const int wid  = tid >> 6;   // wave id 0..3 = H-col tile owner (n-split)
    const int lc   = lane & 15;
    const int lg   = lane >> 4;

    // ---- Weight B-fragments, split hi/lo on the WEIGHT side ----
    // B-frag (16x16x32): lane holds B[k = kk*32 + lg*8 + j][n], j=0..7.
    bf16x8 w1h[4], w1l[4];       // n = wid*16+lc (this wave's n-tile)
#pragma unroll
    for (int kk = 0; kk < 4; ++kk) {
        bf16x8 h, l;
#pragma unroll
        for (int j = 0; j < 8; ++j) {
            int kidx = kk * 32 + lg * 8 + j;
            float v = w1[kidx * 64 + wid * 16 + lc];
            __bf16 hb = (__bf16)v;
            h[j] = hb; l[j] = (__bf16)(v - (float)hb);
        }
        w1h[kk] = h; w1l[kk] = l;
    }
    bf16x8 w2h[2], w2l[2];       // n = lc (<8), padded 0
#pragma unroll
    for (int kk = 0; kk < 2; ++kk) {
        bf16x8 h, l;
#pragma unroll
        for (int j = 0; j < 8; ++j) {
            int kidx = kk * 32 + lg * 8 + j;
            float v = (lc < 8) ? w2[kidx * 8 + lc] : 0.0f;
            __bf16 hb = (__bf16)v;
            h[j] = hb; l[j] = (__bf16)(v - (float)hb);
        }
        w2h[kk] = h; w2l[kk] = l;
    }
    bf16x8 wph[4], wpl[4];       // n = lc (<8), padded 0
#pragma unroll
    for (int kk = 0; kk < 4; ++kk) {
        bf16x8 h, l;
#pragma unroll
        for (int j = 0; j < 8; ++j) {
            int kidx = kk * 32 + lg * 8 + j;
            float v = (lc < 8) ? wp[kidx * 8 + lc] : 0.0f;
            __bf16 hb = (__bf16)v;
            h[j] = hb; l[j] = (__bf16)(v - (float)hb);
        }
        wph[kk] = h; wpl[kk] = l;
    }
    const float b1v = b1[wid * 16 + lc];          // col fixed per wave (n-split)
    const float b2v = (lc < 8) ? b2[lc] : 0.0f;

    const int ntiles = (E + 63) >> 6;
    const int r0 = tid >> 4;          // 0..15 (x-load row)
    const int c8 = tid & 15;          // 8-float column chunk
    const int arow = wid * 16 + lc;   // this wave's phase-F A-frag row

    for (int tile = blockIdx.x; tile < ntiles; tile += gridDim.x) {
        const long long eb = (long long)tile * 64;

        // ---- Load x tile [64][128] f32, coalesced ----
        float4 vr[4][2];
#pragma unroll
        for (int it = 0; it < 4; ++it) {
            long long e = eb + r0 + it * 16;
            if (e > (long long)E - 1) e = E - 1;
            const float4* p = (const float4*)(x + (size_t)e * 128 + c8 * 8);
            vr[it][0] = p[0];
            vr[it][1] = p[1];
        }
        __syncthreads();   // barrier 1: XH(t-1)/HF(t-1) readers done

        // ---- A: convert to bf16 (hi only), write LDS (swizzled) ----
#pragma unroll
        for (int it = 0; it < 4; ++it) {
            int row = r0 + it * 16;
            bf16x8 h;
            const float* f = (const float*)&vr[it][0];
#pragma unroll
            for (int j = 0; j < 8; ++j) h[j] = (__bf16)f[j];
            *(bf16x8*)(XH + swz(row, c8 * 16)) = h;
        }
        __syncthreads();   // barrier 2: x(t) ready

        // ---- D: H = relu(x@w1+b1) for n-tile wid, all 4 m-tiles ----
        // Peel mtt=0 (mt = wid) and stash its A-frags for phase F's x@wp.
        bf16x8 axh[4];
        f32x4 acc[4] = {{0.f,0.f,0.f,0.f},{0.f,0.f,0.f,0.f},{0.f,0.f,0.f,0.f},{0.f,0.f,0.f,0.f}};
#pragma unroll
        for (int kk = 0; kk < 4; ++kk) {
            axh[kk] = *(const bf16x8*)(XH + swz(arow, kk * 64 + lg * 16));
            acc[0] = MFMA(axh[kk], w1h[kk], acc[0]);
            acc[0] = MFMA(axh[kk], w1l[kk], acc[0]);
        }
#pragma unroll
        for (int mtt = 1; mtt < 4; ++mtt) {
            const int mt = (wid + mtt) & 3;
            const int row = mt * 16 + lc;
#pragma unroll
            for (int kk = 0; kk < 4; ++kk) {
                bf16x8 ah = *(const bf16x8*)(XH + swz(row, kk * 64 + lg * 16));
                acc[mtt] = MFMA(ah, w1h[kk], acc[mtt]);
                acc[mtt] = MFMA(ah, w1l[kk], acc[mtt]);
            }
        }
        // bias + relu -> HF f32 (C-layout: row = mt*16+lg*4+r, col = wid*16+lc)
#pragma unroll
        for (int mtt = 0; mtt < 4; ++mtt) {
            const int mt = (wid + mtt) & 3;
#pragma unroll
            for (int r = 0; r < 4; ++r) {
                float hv = fmaxf(acc[mtt][r] + b1v, 0.f);
                *(float*)(HF + swz(mt * 16 + lg * 4 + r, (wid * 16 + lc) * 4)) = hv;
            }
        }
        __syncthreads();   // barrier 3: H ready (cross-wave)

        // ---- F: logits = H@w2 + b2 (H->bf16 once, w2 split); scores from axh ----
        f32x4 lac = {0.f, 0.f, 0.f, 0.f};
        f32x4 sac = {0.f, 0.f, 0.f, 0.f};
#pragma unroll
        for (int kk = 0; kk < 2; ++kk) {
            int base = kk * 128 + lg * 32;     // f32 bytes: k = kk*32 + lg*8
            f32x4 h0 = *(const f32x4*)(HF + swz(arow, base));
            f32x4 h1 = *(const f32x4*)(HF + swz(arow, base + 16));
            bf16x8 hh;
#pragma unroll
            for (int j = 0; j < 4; ++j) {
                hh[j]     = (__bf16)h0[j];
                hh[j + 4] = (__bf16)h1[j];
            }
            lac = MFMA(hh, w2h[kk], lac);
            lac = MFMA(hh, w2l[kk], lac);
        }
#pragma unroll
        for (int kk = 0; kk < 4; ++kk) {
            sac = MFMA(axh[kk], wph[kk], sac);
            sac = MFMA(axh[kk], wpl[kk], sac);
        }

        // ---- Softmax over 8 cols (lanes lc<8; no max-sub) + fused dot ----
#pragma unroll
        for (int r = 0; r < 4; ++r) {
            float lv = lac[r] + b2v;           // TEMPERATURE = 1.0
            float p = __expf(lv);
            float s  = p;
            float fs = p * sac[r];
            s  += __shfl_xor(s, 1);  fs += __shfl_xor(fs, 1);
            s  += __shfl_xor(s, 2);  fs += __shfl_xor(fs, 2);
            s  += __shfl_xor(s, 4);  fs += __shfl_xor(fs, 4);
            float inv = 1.0f / s;
            float alpha = p * inv;
            float fv = fs * inv;
            long long edge = eb + wid * 16 + lg * 4 + r;
            if (edge < E) {
                if (lc < 8) outAlpha[edge * 8 + lc] = alpha;
                if (lc == 0) outFused[edge] = fv;
            }
        }
        // loop-top barrier orders next tile's XH/HF overwrite
    }
}

extern "C" void kernel_launch(void* const* d_in, const int* in_sizes, int n_in,
                              void* d_out, int out_size, void* d_ws, size_t ws_size,
                              hipStream_t stream) {
    const float* x  = (const float*)d_in[0];
    const float* w1 = (const float*)d_in[1];
    const float* b1 = (const float*)d_in[2];
    const float* w2 = (const float*)d_in[3];
    const float* b2 = (const float*)d_in[4];
    const float* wp = (const float*)d_in[5];

    const int E = in_sizes[0] / 128;
    float* outF = (float*)d_out;
    float* outA = outF + E;

    const int ntiles = (E + 63) >> 6;
    const int blocks = ntiles < 768 ? ntiles : 768;
    edge_moe_kernel<<<blocks, 256, 0, stream>>>(x, w1, b1, w2, b2, wp, outF, outA, E);
}